// Round 9
// baseline (783.325 us; speedup 1.0000x reference)
//
#include <hip/hip_runtime.h>
#include <hip/hip_bf16.h>
#include <hip/hip_fp16.h>

typedef _Float16 f16;
typedef f16 f16x4 __attribute__((ext_vector_type(4)));
typedef f16 f16x8 __attribute__((ext_vector_type(8)));
typedef float f32x4 __attribute__((ext_vector_type(4)));

// ---------------- CSR build ----------------

__global__ void count_kernel(const int* __restrict__ dst, int* __restrict__ count, int E) {
    int e = blockIdx.x * blockDim.x + threadIdx.x;
    if (e < E) atomicAdd(&count[dst[e]], 1);
}

__global__ void scan1_kernel(const int* __restrict__ count, int* __restrict__ incl,
                             float* __restrict__ dinv, int* __restrict__ blocksum, int n) {
    __shared__ int lds[1024];
    int t = threadIdx.x;
    int i = blockIdx.x * 1024 + t;
    int v = (i < n) ? count[i] : 0;
    if (i < n) dinv[i] = rsqrtf((float)(v + 1));
    lds[t] = v;
    __syncthreads();
    for (int off = 1; off < 1024; off <<= 1) {
        int add = (t >= off) ? lds[t - off] : 0;
        __syncthreads();
        lds[t] += add;
        __syncthreads();
    }
    if (i < n) incl[i] = lds[t];
    if (t == 1023) blocksum[blockIdx.x] = lds[1023];
}

__global__ void scan2_kernel(const int* __restrict__ blocksum, int* __restrict__ blockoff,
                             int* __restrict__ rowptr, int nb, int n, int E) {
    __shared__ int lds[1024];
    int t = threadIdx.x;
    int v = (t < nb) ? blocksum[t] : 0;
    lds[t] = v;
    __syncthreads();
    for (int off = 1; off < 1024; off <<= 1) {
        int add = (t >= off) ? lds[t - off] : 0;
        __syncthreads();
        lds[t] += add;
        __syncthreads();
    }
    if (t < nb) blockoff[t] = lds[t] - v;   // exclusive
    if (t == 0) rowptr[n] = E;
}

__global__ void scan3_kernel(int* __restrict__ rowptr, const int* __restrict__ count,
                             const int* __restrict__ blockoff, int n) {
    int i = blockIdx.x * blockDim.x + threadIdx.x;
    if (i < n) rowptr[i] = rowptr[i] - count[i] + blockoff[i >> 10];
}

// pass 1: append (src,dst) pairs into per-bucket regions of ebuf.
// bucket b = dst>>6; its region in esrc/ebuf is [rowptr[b*64], rowptr[(b+1)*64])
// so no extra scan is needed. Appends are sequential per bucket -> ~full-line
// write-back (~13 MB) instead of random 4B scatter (102 MB).
__global__ void bin_kernel(const int* __restrict__ src, const int* __restrict__ dst,
                           const int* __restrict__ rowptr, int* __restrict__ bcur,
                           int2* __restrict__ ebuf, int E) {
    int e = blockIdx.x * blockDim.x + threadIdx.x;
    if (e < E) {
        int s = src[e], d = dst[e];
        int pos = rowptr[d & ~63] + atomicAdd(&bcur[d >> 6], 1);
        ebuf[pos] = make_int2(s, d);
    }
}

// pass 2: place src at its final CSR slot. Reads are sequential; writes land
// within the reading block's bucket region (~4 KB) -> lines fully dirtied.
__global__ void place_kernel(const int2* __restrict__ ebuf, const int* __restrict__ rowptr,
                             int* __restrict__ cursor, int* __restrict__ esrc, int E) {
    int e = blockIdx.x * blockDim.x + threadIdx.x;
    if (e < E) {
        int2 p = ebuf[e];
        int pos = rowptr[p.y] + atomicAdd(&cursor[p.y], 1);
        esrc[pos] = p.x;
    }
}

// ---------------- MFMA GEMM: G = f16( (X @ W) * dinv[row] ) ----------------
// X [n,DIN] fp32 row-major, W [DIN,DOUT] fp32 row-major; fp32->fp16 conversion
// happens in registers during LDS staging (no extra global pass).
// 4 waves; wave-tile 64 x WN via 16x16x32_f16 MFMA (RF=4 row frags, CF col frags).
// LDS tiles padded to 80B row stride: fragment ds_read_b128 rows hit rotating
// bank groups (<=2-way alias = free); A and W^T both read as single b128.
template<int DIN, int DOUT, int WAVES_M>
__global__ __launch_bounds__(256) void mfma_gemm_kernel(
        const float* __restrict__ X, const float* __restrict__ W,
        const float* __restrict__ dinv, f16* __restrict__ G, int n) {
    constexpr int WAVES_N = 4 / WAVES_M;
    constexpr int BM = WAVES_M * 64;
    constexpr int WN = DOUT / WAVES_N;     // 64 or 32
    constexpr int RF = 4;                  // row fragments (64/16)
    constexpr int CF = WN / 16;            // col fragments
    constexpr int BK = 32;
    constexpr int LDK = BK + 8;            // padded stride in halves (80B)
    constexpr int KPT = BK * DOUT / 256;   // W k-elements per thread (16/8/4)

    __shared__ f16 As[BM][LDK];            // A tile, row-major [m][k]
    __shared__ f16 Bs[DOUT][LDK];          // W tile TRANSPOSED: [n][k]

    int tid  = threadIdx.x;
    int lane = tid & 63;
    int w    = tid >> 6;
    int wy   = w / WAVES_N;
    int wx   = w % WAVES_N;
    int row0 = blockIdx.x * BM;
    int l15  = lane & 15;
    int kq   = lane >> 4;                  // 0..3

    f32x4 acc[RF][CF];
    #pragma unroll
    for (int i = 0; i < RF; i++)
        #pragma unroll
        for (int j = 0; j < CF; j++)
            acc[i][j] = (f32x4){0.f, 0.f, 0.f, 0.f};

    for (int k0 = 0; k0 < DIN; k0 += BK) {
        // stage A: 8 consecutive threads cover one row's 128B (coalesced),
        // convert to fp16, write 8B to LDS.
        #pragma unroll
        for (int i = tid; i < BM * 8; i += 256) {
            int r  = i >> 3;
            int c4 = (i & 7) << 2;
            int rg = row0 + r;
            float4 v = make_float4(0.f, 0.f, 0.f, 0.f);
            if (rg < n) v = *(const float4*)&X[(size_t)rg * DIN + k0 + c4];
            f16x4 h = { (f16)v.x, (f16)v.y, (f16)v.z, (f16)v.w };
            *(f16x4*)&As[r][c4] = h;
        }
        // stage W transposed: thread owns column nc, KPT consecutive k's.
        {
            int nc = tid % DOUT;
            int kb = (tid / DOUT) * KPT;
            f16 tmp[KPT];
            #pragma unroll
            for (int j = 0; j < KPT; j++)
                tmp[j] = (f16)W[(size_t)(k0 + kb + j) * DOUT + nc];
            if constexpr (KPT == 16) {
                *(f16x8*)&Bs[nc][kb]     = *(f16x8*)&tmp[0];
                *(f16x8*)&Bs[nc][kb + 8] = *(f16x8*)&tmp[8];
            } else if constexpr (KPT == 8) {
                *(f16x8*)&Bs[nc][kb]     = *(f16x8*)&tmp[0];
            } else {
                *(f16x4*)&Bs[nc][kb]     = *(f16x4*)&tmp[0];
            }
        }
        __syncthreads();

        // fragments: A lane l -> row (l&15), k = (l>>4)*8+j ; B lane l -> col
        // (l&15), k = (l>>4)*8+j.  Both are single 16B contiguous LDS reads.
        f16x8 a[RF], b[CF];
        #pragma unroll
        for (int i = 0; i < RF; i++)
            a[i] = *(f16x8*)&As[wy * 64 + i * 16 + l15][kq * 8];
        #pragma unroll
        for (int j = 0; j < CF; j++)
            b[j] = *(f16x8*)&Bs[wx * WN + j * 16 + l15][kq * 8];
        #pragma unroll
        for (int i = 0; i < RF; i++)
            #pragma unroll
            for (int j = 0; j < CF; j++)
                acc[i][j] = __builtin_amdgcn_mfma_f32_16x16x32_f16(a[i], b[j], acc[i][j], 0, 0, 0);
        __syncthreads();
    }

    // epilogue: C/D layout col = lane&15, row = (lane>>4)*4 + reg
    #pragma unroll
    for (int i = 0; i < RF; i++) {
        #pragma unroll
        for (int r = 0; r < 4; r++) {
            int row = row0 + wy * 64 + i * 16 + (lane >> 4) * 4 + r;
            if (row < n) {
                float di = dinv[row];
                #pragma unroll
                for (int j = 0; j < CF; j++) {
                    int col = wx * WN + j * 16 + l15;
                    G[(size_t)row * DOUT + col] = (f16)(acc[i][j][r] * di);
                }
            }
        }
    }
}

// ---------------- aggregation: h[i] = tanh(dinv[i]*(sum_e G[src_e] + G[i]) + b) ----------------
// G fp16 [n,DOUT]; each lane owns 4 halves (8B gathers); fp32 accumulate; fp32 output.
template<int DOUT>
__global__ void agg_kernel(const __half* __restrict__ g, const float* __restrict__ dinv,
                           const int* __restrict__ rowptr, const int* __restrict__ esrc,
                           const float* __restrict__ bias, float* __restrict__ out, int n) {
    constexpr int LPN = DOUT / 4;           // lanes per node
    constexpr int NPW = 64 / LPN;           // nodes per wave
    int wave = threadIdx.x >> 6;
    int lane = threadIdx.x & 63;
    int sub  = lane / LPN;
    int cl   = lane % LPN;                  // 4-half chunk index
    int node = (blockIdx.x * (blockDim.x >> 6) + wave) * NPW + sub;
    if (node >= n) return;

    const uint2* g2 = (const uint2*)g;      // 4 halves per element
    auto fetch = [&](int s, float4& a) {
        uint2 v = g2[(size_t)s * LPN + cl];
        __half2 h0 = *reinterpret_cast<__half2*>(&v.x);
        __half2 h1 = *reinterpret_cast<__half2*>(&v.y);
        float2 f0 = __half22float2(h0);
        float2 f1 = __half22float2(h1);
        a.x += f0.x; a.y += f0.y; a.z += f1.x; a.w += f1.y;
    };

    float4 acc = make_float4(0.f, 0.f, 0.f, 0.f);
    fetch(node, acc);                       // self-loop term

    int e = rowptr[node], end = rowptr[node + 1];
    for (; e + 4 <= end; e += 4) {
        int s0 = esrc[e], s1 = esrc[e + 1], s2 = esrc[e + 2], s3 = esrc[e + 3];
        fetch(s0, acc); fetch(s1, acc); fetch(s2, acc); fetch(s3, acc);
    }
    for (; e < end; e++) fetch(esrc[e], acc);

    float di = dinv[node];
    float4 b = *(const float4*)&bias[cl * 4];
    float4 o;
    o.x = tanhf(di * acc.x + b.x);
    o.y = tanhf(di * acc.y + b.y);
    o.z = tanhf(di * acc.z + b.z);
    o.w = tanhf(di * acc.w + b.w);
    *(float4*)&out[(size_t)node * DOUT + cl * 4] = o;
}

// ---------------- classifier: out = H @ Wc + bc  (32 -> 86) ----------------
__global__ __launch_bounds__(256) void cls_kernel(
        const float* __restrict__ H, const float* __restrict__ Wc,
        const float* __restrict__ bc, float* __restrict__ out, int n) {
    constexpr int DIN = 32, DOUT = 86, RPB = 64;
    __shared__ float Hs[RPB][DIN + 4];
    __shared__ float Ws[DIN][DOUT];
    __shared__ float bs[DOUT];
    int tid = threadIdx.x;
    int row0 = blockIdx.x * RPB;
    for (int i = tid; i < DIN * DOUT; i += 256) Ws[i / DOUT][i % DOUT] = Wc[i];
    if (tid < DOUT) bs[tid] = bc[tid];
    for (int i = tid; i < RPB * (DIN / 4); i += 256) {
        int r = i >> 3, c4 = (i & 7) << 2;
        int rg = row0 + r;
        float4 v = make_float4(0.f, 0.f, 0.f, 0.f);
        if (rg < n) v = *(const float4*)&H[(size_t)rg * DIN + c4];
        *(float4*)&Hs[r][c4] = v;
    }
    __syncthreads();
    for (int idx = tid; idx < RPB * DOUT; idx += 256) {
        int r = idx / DOUT, c = idx - r * DOUT;
        float a = bs[c];
        #pragma unroll
        for (int k = 0; k < DIN; k++) a += Hs[r][k] * Ws[k][c];
        int rg = row0 + r;
        if (rg < n) out[(size_t)rg * DOUT + c] = a;
    }
}

extern "C" void kernel_launch(void* const* d_in, const int* in_sizes, int n_in,
                              void* d_out, int out_size, void* d_ws, size_t ws_size,
                              hipStream_t stream) {
    const float* x  = (const float*)d_in[0];
    const int*   ei = (const int*)d_in[1];
    const float* W1 = (const float*)d_in[2];
    const float* b1 = (const float*)d_in[3];
    const float* W2 = (const float*)d_in[4];
    const float* b2 = (const float*)d_in[5];
    const float* W3 = (const float*)d_in[6];
    const float* b3 = (const float*)d_in[7];
    const float* Wc = (const float*)d_in[8];
    const float* bc = (const float*)d_in[9];

    const int n = in_sizes[0] / 256;     // 100000
    const int E = in_sizes[1] / 2;       // 1600000
    const int* src = ei;
    const int* dst = ei + E;

    char* ws = (char*)d_ws;
    size_t off = 0;
    auto alloc = [&](size_t bytes) {
        void* p = ws + off;
        off = (off + bytes + 255) & ~(size_t)255;
        return p;
    };
    const int nbuck = (n + 63) >> 6;
    float*  dinv    = (float*)alloc((size_t)n * 4);
    int*    count   = (int*)  alloc((size_t)n * 4);
    int*    rowptr  = (int*)  alloc((size_t)(n + 1) * 4);
    int*    cursor  = (int*)  alloc((size_t)n * 4);
    int*    bcur    = (int*)  alloc((size_t)nbuck * 4);
    int*    blocksum= (int*)  alloc(1024 * 4);
    int*    blockoff= (int*)  alloc(1024 * 4);
    int*    esrc    = (int*)  alloc((size_t)E * 4);
    int2*   ebuf    = (int2*) alloc((size_t)E * 8);
    __half* Gh      = (__half*)alloc((size_t)n * 128 * 2);  // fp16 gather buffer
    float*  Hf      = (float*)alloc((size_t)n * 128 * 4);   // fp32 activations

    float* outp = (float*)d_out;             // [n, 86]
    float* h3   = outp + (size_t)n * 86;     // [n, 32] (second tuple output)

    hipMemsetAsync(count, 0, (size_t)n * 4, stream);
    hipMemsetAsync(cursor, 0, (size_t)n * 4, stream);
    hipMemsetAsync(bcur, 0, (size_t)nbuck * 4, stream);

    int eblocks = (E + 255) / 256;
    count_kernel<<<eblocks, 256, 0, stream>>>(dst, count, E);
    int nb = (n + 1023) / 1024;
    scan1_kernel<<<nb, 1024, 0, stream>>>(count, rowptr, dinv, blocksum, n);
    scan2_kernel<<<1, 1024, 0, stream>>>(blocksum, blockoff, rowptr, nb, n, E);
    scan3_kernel<<<(n + 255) / 256, 256, 0, stream>>>(rowptr, count, blockoff, n);
    bin_kernel<<<eblocks, 256, 0, stream>>>(src, dst, rowptr, bcur, ebuf, E);
    place_kernel<<<eblocks, 256, 0, stream>>>(ebuf, rowptr, cursor, esrc, E);

    // layer 1: 256 -> 128   (BM=128, waves 2x2)
    mfma_gemm_kernel<256, 128, 2><<<(n + 127) / 128, 256, 0, stream>>>(x, W1, dinv, (f16*)Gh, n);
    agg_kernel<128><<<(n + 7) / 8, 256, 0, stream>>>(Gh, dinv, rowptr, esrc, b1, Hf, n);
    // layer 2: 128 -> 64    (BM=256, waves 4x1)
    mfma_gemm_kernel<128, 64, 4><<<(n + 255) / 256, 256, 0, stream>>>(Hf, W2, dinv, (f16*)Gh, n);
    agg_kernel<64><<<(n + 15) / 16, 256, 0, stream>>>(Gh, dinv, rowptr, esrc, b2, Hf, n);
    // layer 3: 64 -> 32     (BM=256, waves 4x1)
    mfma_gemm_kernel<64, 32, 4><<<(n + 255) / 256, 256, 0, stream>>>(Hf, W3, dinv, (f16*)Gh, n);
    agg_kernel<32><<<(n + 31) / 32, 256, 0, stream>>>(Gh, dinv, rowptr, esrc, b3, h3, n);
    // classifier: 32 -> 86
    cls_kernel<<<(n + 63) / 64, 256, 0, stream>>>(h3, Wc, bc, outp, n);
}

// Round 12
// 576.443 us; speedup vs baseline: 1.3589x; 1.3589x over previous
//
#include <hip/hip_runtime.h>
#include <hip/hip_bf16.h>
#include <hip/hip_fp16.h>

typedef _Float16 f16;
typedef f16 f16x4 __attribute__((ext_vector_type(4)));
typedef f16 f16x8 __attribute__((ext_vector_type(8)));
typedef float f32x4 __attribute__((ext_vector_type(4)));

// ---------------- CSR build ----------------

__global__ void count_kernel(const int* __restrict__ dst, int* __restrict__ count, int E) {
    int e = blockIdx.x * blockDim.x + threadIdx.x;
    if (e < E) atomicAdd(&count[dst[e]], 1);
}

__global__ void scan1_kernel(const int* __restrict__ count, int* __restrict__ incl,
                             float* __restrict__ dinv, int* __restrict__ blocksum, int n) {
    __shared__ int lds[1024];
    int t = threadIdx.x;
    int i = blockIdx.x * 1024 + t;
    int v = (i < n) ? count[i] : 0;
    if (i < n) dinv[i] = rsqrtf((float)(v + 1));
    lds[t] = v;
    __syncthreads();
    for (int off = 1; off < 1024; off <<= 1) {
        int add = (t >= off) ? lds[t - off] : 0;
        __syncthreads();
        lds[t] += add;
        __syncthreads();
    }
    if (i < n) incl[i] = lds[t];
    if (t == 1023) blocksum[blockIdx.x] = lds[1023];
}

__global__ void scan2_kernel(const int* __restrict__ blocksum, int* __restrict__ blockoff,
                             int* __restrict__ rowptr, int nb, int n, int E) {
    __shared__ int lds[1024];
    int t = threadIdx.x;
    int v = (t < nb) ? blocksum[t] : 0;
    lds[t] = v;
    __syncthreads();
    for (int off = 1; off < 1024; off <<= 1) {
        int add = (t >= off) ? lds[t - off] : 0;
        __syncthreads();
        lds[t] += add;
        __syncthreads();
    }
    if (t < nb) blockoff[t] = lds[t] - v;   // exclusive
    if (t == 0) rowptr[n] = E;
}

__global__ void scan3_kernel(int* __restrict__ rowptr, const int* __restrict__ count,
                             const int* __restrict__ blockoff, int n) {
    int i = blockIdx.x * blockDim.x + threadIdx.x;
    if (i < n) rowptr[i] = rowptr[i] - count[i] + blockoff[i >> 10];
}

// XCD-sliced scatter. Slice s owns nodes [s*ss, (s+1)*ss); block b serves slice
// b&7. Dispatch round-robins blocks over the 8 XCDs, so one slice's esrc region
// (~0.8 MB) + cursor (~50 KB) is written from ONE XCD only and stays L2-resident
// -> lines fully dirtied before write-back (R9 lesson: cross-XCD same-line
// writes bounce; this removes them). Each edge chunk is re-read by the 8
// slice-blocks sharing it (consecutive blockIdx, ~concurrent) -> L3-warm.
__global__ void scatter2_kernel(const int* __restrict__ src, const int* __restrict__ dst,
                                const int* __restrict__ rowptr, int* __restrict__ cursor,
                                int* __restrict__ esrc, int E, int ss, int nwithin) {
    int slice  = blockIdx.x & 7;
    int within = blockIdx.x >> 3;
    int lo = slice * ss;
    int hi = lo + ss;
    int chunk = (E + nwithin - 1) / nwithin;
    int start = within * chunk;
    int end   = min(E, start + chunk);
    for (int e = start + (int)threadIdx.x; e < end; e += (int)blockDim.x) {
        int d = dst[e];
        if (d >= lo && d < hi) {
            int pos = rowptr[d] + atomicAdd(&cursor[d], 1);
            esrc[pos] = src[e];
        }
    }
}

// ---------------- MFMA GEMM: G = f16( (X @ W) * dinv[row] ) ----------------
// X [n,DIN] fp32 row-major, W [DIN,DOUT] fp32 row-major; fp32->fp16 conversion
// happens in registers during LDS staging (no extra global pass).
// 4 waves; wave-tile 64 x WN via 16x16x32_f16 MFMA (RF=4 row frags, CF col frags).
// LDS tiles padded to 80B row stride: fragment ds_read_b128 rows hit rotating
// bank groups (<=2-way alias = free); A and W^T both read as single b128.
template<int DIN, int DOUT, int WAVES_M>
__global__ __launch_bounds__(256) void mfma_gemm_kernel(
        const float* __restrict__ X, const float* __restrict__ W,
        const float* __restrict__ dinv, f16* __restrict__ G, int n) {
    constexpr int WAVES_N = 4 / WAVES_M;
    constexpr int BM = WAVES_M * 64;
    constexpr int WN = DOUT / WAVES_N;     // 64 or 32
    constexpr int RF = 4;                  // row fragments (64/16)
    constexpr int CF = WN / 16;            // col fragments
    constexpr int BK = 32;
    constexpr int LDK = BK + 8;            // padded stride in halves (80B)
    constexpr int KPT = BK * DOUT / 256;   // W k-elements per thread (16/8/4)

    __shared__ f16 As[BM][LDK];            // A tile, row-major [m][k]
    __shared__ f16 Bs[DOUT][LDK];          // W tile TRANSPOSED: [n][k]

    int tid  = threadIdx.x;
    int lane = tid & 63;
    int w    = tid >> 6;
    int wy   = w / WAVES_N;
    int wx   = w % WAVES_N;
    int row0 = blockIdx.x * BM;
    int l15  = lane & 15;
    int kq   = lane >> 4;                  // 0..3

    f32x4 acc[RF][CF];
    #pragma unroll
    for (int i = 0; i < RF; i++)
        #pragma unroll
        for (int j = 0; j < CF; j++)
            acc[i][j] = (f32x4){0.f, 0.f, 0.f, 0.f};

    for (int k0 = 0; k0 < DIN; k0 += BK) {
        // stage A: 8 consecutive threads cover one row's 128B (coalesced),
        // convert to fp16, write 8B to LDS.
        #pragma unroll
        for (int i = tid; i < BM * 8; i += 256) {
            int r  = i >> 3;
            int c4 = (i & 7) << 2;
            int rg = row0 + r;
            float4 v = make_float4(0.f, 0.f, 0.f, 0.f);
            if (rg < n) v = *(const float4*)&X[(size_t)rg * DIN + k0 + c4];
            f16x4 h = { (f16)v.x, (f16)v.y, (f16)v.z, (f16)v.w };
            *(f16x4*)&As[r][c4] = h;
        }
        // stage W transposed: thread owns column nc, KPT consecutive k's.
        {
            int nc = tid % DOUT;
            int kb = (tid / DOUT) * KPT;
            f16 tmp[KPT];
            #pragma unroll
            for (int j = 0; j < KPT; j++)
                tmp[j] = (f16)W[(size_t)(k0 + kb + j) * DOUT + nc];
            if constexpr (KPT == 16) {
                *(f16x8*)&Bs[nc][kb]     = *(f16x8*)&tmp[0];
                *(f16x8*)&Bs[nc][kb + 8] = *(f16x8*)&tmp[8];
            } else if constexpr (KPT == 8) {
                *(f16x8*)&Bs[nc][kb]     = *(f16x8*)&tmp[0];
            } else {
                *(f16x4*)&Bs[nc][kb]     = *(f16x4*)&tmp[0];
            }
        }
        __syncthreads();

        // fragments: A lane l -> row (l&15), k = (l>>4)*8+j ; B lane l -> col
        // (l&15), k = (l>>4)*8+j.  Both are single 16B contiguous LDS reads.
        f16x8 a[RF], b[CF];
        #pragma unroll
        for (int i = 0; i < RF; i++)
            a[i] = *(f16x8*)&As[wy * 64 + i * 16 + l15][kq * 8];
        #pragma unroll
        for (int j = 0; j < CF; j++)
            b[j] = *(f16x8*)&Bs[wx * WN + j * 16 + l15][kq * 8];
        #pragma unroll
        for (int i = 0; i < RF; i++)
            #pragma unroll
            for (int j = 0; j < CF; j++)
                acc[i][j] = __builtin_amdgcn_mfma_f32_16x16x32_f16(a[i], b[j], acc[i][j], 0, 0, 0);
        __syncthreads();
    }

    // epilogue: C/D layout col = lane&15, row = (lane>>4)*4 + reg
    #pragma unroll
    for (int i = 0; i < RF; i++) {
        #pragma unroll
        for (int r = 0; r < 4; r++) {
            int row = row0 + wy * 64 + i * 16 + (lane >> 4) * 4 + r;
            if (row < n) {
                float di = dinv[row];
                #pragma unroll
                for (int j = 0; j < CF; j++) {
                    int col = wx * WN + j * 16 + l15;
                    G[(size_t)row * DOUT + col] = (f16)(acc[i][j][r] * di);
                }
            }
        }
    }
}

// ---------------- aggregation: h[i] = tanh(dinv[i]*(sum_e G[src_e] + G[i]) + b) ----------------
// G fp16 [n,DOUT]; each lane owns 4 halves (8B gathers); fp32 accumulate; fp32 output.
template<int DOUT>
__global__ void agg_kernel(const __half* __restrict__ g, const float* __restrict__ dinv,
                           const int* __restrict__ rowptr, const int* __restrict__ esrc,
                           const float* __restrict__ bias, float* __restrict__ out, int n) {
    constexpr int LPN = DOUT / 4;           // lanes per node
    constexpr int NPW = 64 / LPN;           // nodes per wave
    int wave = threadIdx.x >> 6;
    int lane = threadIdx.x & 63;
    int sub  = lane / LPN;
    int cl   = lane % LPN;                  // 4-half chunk index
    int node = (blockIdx.x * (blockDim.x >> 6) + wave) * NPW + sub;
    if (node >= n) return;

    const uint2* g2 = (const uint2*)g;      // 4 halves per element
    auto fetch = [&](int s, float4& a) {
        uint2 v = g2[(size_t)s * LPN + cl];
        __half2 h0 = *reinterpret_cast<__half2*>(&v.x);
        __half2 h1 = *reinterpret_cast<__half2*>(&v.y);
        float2 f0 = __half22float2(h0);
        float2 f1 = __half22float2(h1);
        a.x += f0.x; a.y += f0.y; a.z += f1.x; a.w += f1.y;
    };

    float4 acc = make_float4(0.f, 0.f, 0.f, 0.f);
    fetch(node, acc);                       // self-loop term

    int e = rowptr[node], end = rowptr[node + 1];
    for (; e + 4 <= end; e += 4) {
        int s0 = esrc[e], s1 = esrc[e + 1], s2 = esrc[e + 2], s3 = esrc[e + 3];
        fetch(s0, acc); fetch(s1, acc); fetch(s2, acc); fetch(s3, acc);
    }
    for (; e < end; e++) fetch(esrc[e], acc);

    float di = dinv[node];
    float4 b = *(const float4*)&bias[cl * 4];
    float4 o;
    o.x = tanhf(di * acc.x + b.x);
    o.y = tanhf(di * acc.y + b.y);
    o.z = tanhf(di * acc.z + b.z);
    o.w = tanhf(di * acc.w + b.w);
    *(float4*)&out[(size_t)node * DOUT + cl * 4] = o;
}

// ---------------- classifier: out = H @ Wc + bc  (32 -> 86) ----------------
__global__ __launch_bounds__(256) void cls_kernel(
        const float* __restrict__ H, const float* __restrict__ Wc,
        const float* __restrict__ bc, float* __restrict__ out, int n) {
    constexpr int DIN = 32, DOUT = 86, RPB = 64;
    __shared__ float Hs[RPB][DIN + 4];
    __shared__ float Ws[DIN][DOUT];
    __shared__ float bs[DOUT];
    int tid = threadIdx.x;
    int row0 = blockIdx.x * RPB;
    for (int i = tid; i < DIN * DOUT; i += 256) Ws[i / DOUT][i % DOUT] = Wc[i];
    if (tid < DOUT) bs[tid] = bc[tid];
    for (int i = tid; i < RPB * (DIN / 4); i += 256) {
        int r = i >> 3, c4 = (i & 7) << 2;
        int rg = row0 + r;
        float4 v = make_float4(0.f, 0.f, 0.f, 0.f);
        if (rg < n) v = *(const float4*)&H[(size_t)rg * DIN + c4];
        *(float4*)&Hs[r][c4] = v;
    }
    __syncthreads();
    for (int idx = tid; idx < RPB * DOUT; idx += 256) {
        int r = idx / DOUT, c = idx - r * DOUT;
        float a = bs[c];
        #pragma unroll
        for (int k = 0; k < DIN; k++) a += Hs[r][k] * Ws[k][c];
        int rg = row0 + r;
        if (rg < n) out[(size_t)rg * DOUT + c] = a;
    }
}

extern "C" void kernel_launch(void* const* d_in, const int* in_sizes, int n_in,
                              void* d_out, int out_size, void* d_ws, size_t ws_size,
                              hipStream_t stream) {
    const float* x  = (const float*)d_in[0];
    const int*   ei = (const int*)d_in[1];
    const float* W1 = (const float*)d_in[2];
    const float* b1 = (const float*)d_in[3];
    const float* W2 = (const float*)d_in[4];
    const float* b2 = (const float*)d_in[5];
    const float* W3 = (const float*)d_in[6];
    const float* b3 = (const float*)d_in[7];
    const float* Wc = (const float*)d_in[8];
    const float* bc = (const float*)d_in[9];

    const int n = in_sizes[0] / 256;     // 100000
    const int E = in_sizes[1] / 2;       // 1600000
    const int* src = ei;
    const int* dst = ei + E;

    char* ws = (char*)d_ws;
    size_t off = 0;
    auto alloc = [&](size_t bytes) {
        void* p = ws + off;
        off = (off + bytes + 255) & ~(size_t)255;
        return p;
    };
    float*  dinv    = (float*)alloc((size_t)n * 4);
    int*    count   = (int*)  alloc((size_t)n * 4);
    int*    rowptr  = (int*)  alloc((size_t)(n + 1) * 4);
    int*    cursor  = (int*)  alloc((size_t)n * 4);
    int*    blocksum= (int*)  alloc(1024 * 4);
    int*    blockoff= (int*)  alloc(1024 * 4);
    int*    esrc    = (int*)  alloc((size_t)E * 4);
    __half* Gh      = (__half*)alloc((size_t)n * 128 * 2);  // fp16 gather buffer
    float*  Hf      = (float*)alloc((size_t)n * 128 * 4);   // fp32 activations

    float* outp = (float*)d_out;             // [n, 86]
    float* h3   = outp + (size_t)n * 86;     // [n, 32] (second tuple output)

    hipMemsetAsync(count, 0, (size_t)n * 4, stream);
    hipMemsetAsync(cursor, 0, (size_t)n * 4, stream);

    int eblocks = (E + 255) / 256;
    count_kernel<<<eblocks, 256, 0, stream>>>(dst, count, E);
    int nb = (n + 1023) / 1024;
    scan1_kernel<<<nb, 1024, 0, stream>>>(count, rowptr, dinv, blocksum, n);
    scan2_kernel<<<1, 1024, 0, stream>>>(blocksum, blockoff, rowptr, nb, n, E);
    scan3_kernel<<<(n + 255) / 256, 256, 0, stream>>>(rowptr, count, blockoff, n);
    {
        const int nwithin = 128;             // blocks per slice
        const int ss = (n + 7) / 8;          // nodes per slice (12500)
        scatter2_kernel<<<8 * nwithin, 256, 0, stream>>>(src, dst, rowptr, cursor, esrc, E, ss, nwithin);
    }

    // layer 1: 256 -> 128   (BM=128, waves 2x2)
    mfma_gemm_kernel<256, 128, 2><<<(n + 127) / 128, 256, 0, stream>>>(x, W1, dinv, (f16*)Gh, n);
    agg_kernel<128><<<(n + 7) / 8, 256, 0, stream>>>(Gh, dinv, rowptr, esrc, b1, Hf, n);
    // layer 2: 128 -> 64    (BM=256, waves 4x1)
    mfma_gemm_kernel<128, 64, 4><<<(n + 255) / 256, 256, 0, stream>>>(Hf, W2, dinv, (f16*)Gh, n);
    agg_kernel<64><<<(n + 15) / 16, 256, 0, stream>>>(Gh, dinv, rowptr, esrc, b2, Hf, n);
    // layer 3: 64 -> 32     (BM=256, waves 4x1)
    mfma_gemm_kernel<64, 32, 4><<<(n + 255) / 256, 256, 0, stream>>>(Hf, W3, dinv, (f16*)Gh, n);
    agg_kernel<32><<<(n + 31) / 32, 256, 0, stream>>>(Gh, dinv, rowptr, esrc, b3, h3, n);
    // classifier: 32 -> 86
    cls_kernel<<<(n + 63) / 64, 256, 0, stream>>>(h3, Wc, bc, outp, n);
}